// Round 4
// baseline (498.408 us; speedup 1.0000x reference)
//
#include <hip/hip_runtime.h>
#include <math.h>

// Problem constants (from reference): B=4, N=4096, C=2048, E=64, K=2
#define T_TOKENS 16384
#define C_DIM    2048
#define N_SEQ    4096
#define E_EXP    64
#define KC       32      // K-chunk (channels per LDS stage) — 18.4 KB/block
#define TM       64      // tokens per block
#define LSTR     36      // LDS row stride: 32+4 pad; rows collide only 2-way (free)
#define NSLICE   4       // split-K slices -> 1024 gemm blocks
#define EPB      1024    // epilogue blocks (16 tokens each)

// ---------------------------------------------------------------------------
// Kernel 1: ctx[b][j] = dot(routing_context[b,:], ctx_w[j,:])   (4 x 2048 out)
// ---------------------------------------------------------------------------
__global__ __launch_bounds__(256) void ctx_kernel(
    const float* __restrict__ rc, const float* __restrict__ ctx_w,
    float* __restrict__ ctx_out)
{
    const int w    = threadIdx.x >> 6;
    const int lane = threadIdx.x & 63;
    const int o    = blockIdx.x * 4 + w;         // 0..8191
    const int b    = o >> 11;
    const int j    = o & 2047;

    const float4* wr = (const float4*)(ctx_w + (size_t)j * C_DIM);
    const float4* rr = (const float4*)(rc + (size_t)b * C_DIM);
    float s = 0.f;
#pragma unroll
    for (int it = 0; it < 8; ++it) {
        float4 a = wr[it * 64 + lane];
        float4 c = rr[it * 64 + lane];
        s += a.x * c.x + a.y * c.y + a.z * c.z + a.w * c.w;
    }
#pragma unroll
    for (int off = 32; off; off >>= 1) s += __shfl_xor(s, off, 64);
    if (lane == 0) ctx_out[b * C_DIM + j] = s;
}

// ---------------------------------------------------------------------------
// Kernel 2a (split-K GEMM): block = 64 tokens x 64 experts x 512-ch slice.
// KC=32 -> LDS 18.4 KB/block so multiple blocks/CU co-reside (R3: 34.8 KB gave
// only ~1.6 blocks/CU; barrier drains unhidden). No minwaves bound (R2 spill).
// ---------------------------------------------------------------------------
__global__ __launch_bounds__(256) void gemm_kernel(
    const float* __restrict__ x, const float* __restrict__ gate_w,
    const float* __restrict__ ctx, float* __restrict__ P)
{
    __shared__ float xs[TM][LSTR];     // token tile (x + ctx)
    __shared__ float gs[E_EXP][LSTR];  // gate tile

    const int tid   = threadIdx.x;
    const int eg    = tid & 15;        // expert group: e = eg + 16j
    const int tg    = tid >> 4;        // token group:  t = tg + 16i
    const int tile  = blockIdx.x & 255;
    const int slice = blockIdx.x >> 8;
    const int t0    = tile * TM;
    const int b     = t0 / N_SEQ;
    const int cbase = slice * (C_DIM / NSLICE);

    const int scg = tid & 7;           // staging float4 col (0..7)
    const int sr  = tid >> 3;          // staging row (0..31); also row+32

    const float* ctx_row = ctx + (size_t)b * C_DIM;

    float4 acc[4][4];
#pragma unroll
    for (int i = 0; i < 4; ++i)
#pragma unroll
        for (int j = 0; j < 4; ++j)
            acc[i][j] = make_float4(0.f, 0.f, 0.f, 0.f);

    float4 px[2], pg[2], pc;
    auto prefetch = [&](int kc) {
        const int c0 = cbase + kc * KC + scg * 4;
        pc    = *(const float4*)(ctx_row + c0);
        px[0] = *(const float4*)(x + (size_t)(t0 + sr) * C_DIM + c0);
        px[1] = *(const float4*)(x + (size_t)(t0 + sr + 32) * C_DIM + c0);
        pg[0] = *(const float4*)(gate_w + (size_t)sr * C_DIM + c0);
        pg[1] = *(const float4*)(gate_w + (size_t)(sr + 32) * C_DIM + c0);
    };

    prefetch(0);
    const int NCHUNK = (C_DIM / NSLICE) / KC;   // 16
    for (int kc = 0; kc < NCHUNK; ++kc) {
        __syncthreads();
        {
            float4 v0 = px[0], v1 = px[1];
            v0.x += pc.x; v0.y += pc.y; v0.z += pc.z; v0.w += pc.w;
            v1.x += pc.x; v1.y += pc.y; v1.z += pc.z; v1.w += pc.w;
            *(float4*)&xs[sr][scg * 4]      = v0;
            *(float4*)&xs[sr + 32][scg * 4] = v1;
            *(float4*)&gs[sr][scg * 4]      = pg[0];
            *(float4*)&gs[sr + 32][scg * 4] = pg[1];
        }
        __syncthreads();
        if (kc + 1 < NCHUNK) prefetch(kc + 1);
#pragma unroll
        for (int cc = 0; cc < KC; cc += 4) {
            float4 xv[4], gv[4];
#pragma unroll
            for (int i = 0; i < 4; ++i) xv[i] = *(const float4*)&xs[tg + 16 * i][cc];
#pragma unroll
            for (int j = 0; j < 4; ++j) gv[j] = *(const float4*)&gs[eg + 16 * j][cc];
#pragma unroll
            for (int i = 0; i < 4; ++i)
#pragma unroll
                for (int j = 0; j < 4; ++j) {
                    acc[i][j].x = fmaf(xv[i].x, gv[j].x, acc[i][j].x);
                    acc[i][j].y = fmaf(xv[i].y, gv[j].y, acc[i][j].y);
                    acc[i][j].z = fmaf(xv[i].z, gv[j].z, acc[i][j].z);
                    acc[i][j].w = fmaf(xv[i].w, gv[j].w, acc[i][j].w);
                }
        }
    }

    float* Ps = P + (size_t)slice * T_TOKENS * E_EXP;
#pragma unroll
    for (int i = 0; i < 4; ++i)
#pragma unroll
        for (int j = 0; j < 4; ++j)
            Ps[(size_t)(t0 + tg + 16 * i) * E_EXP + eg + 16 * j] =
                (acc[i][j].x + acc[i][j].y) + (acc[i][j].z + acc[i][j].w);
}

// ---------------------------------------------------------------------------
// Kernel 2b (epilogue): sum NSLICE partials in fixed order (deterministic),
// single fused 6-step butterfly carrying (v1,i1,v2,i2,sum_exp).
// NO global atomics (R3: 524K atomics on 4 cache lines = 108 us). Per-block
// LDS reduce -> bp[block][128] partials; aux_kernel finishes.
// ---------------------------------------------------------------------------
__global__ __launch_bounds__(256) void epilogue_kernel(
    const float* __restrict__ P, float* __restrict__ out,
    float* __restrict__ bp)
{
    __shared__ float red[4][128];

    const int tid  = threadIdx.x;
    const int wv   = tid >> 6;
    const int lane = tid & 63;
    const int t0   = blockIdx.x * (T_TOKENS / EPB);   // 16 tokens per block

    float imp_acc = 0.f, cnt_acc = 0.f;

    for (int tt = 0; tt < 4; ++tt) {
        const int t = t0 + wv * 4 + tt;
        float v = 0.f;
#pragma unroll
        for (int s = 0; s < NSLICE; ++s)
            v += P[((size_t)s * T_TOKENS + t) * E_EXP + lane];

        // fused top-2 + sum(exp) butterfly (tie -> lower index, matches lax.top_k)
        const float p = expf(v);       // |v| ~< 12 -> no overflow
        float v1 = v;  int i1 = lane;
        float v2 = -INFINITY; int i2 = 0x7fffffff;
        float s = p;
#pragma unroll
        for (int off = 32; off; off >>= 1) {
            float ov1 = __shfl_xor(v1, off, 64);
            int   oi1 = __shfl_xor(i1, off, 64);
            float ov2 = __shfl_xor(v2, off, 64);
            int   oi2 = __shfl_xor(i2, off, 64);
            s += __shfl_xor(s, off, 64);
            // merge (v1,i1,v2,i2) with (ov1,oi1,ov2,oi2)
            const bool aw = (ov1 < v1) || (ov1 == v1 && i1 < oi1);
            const float lv = aw ? ov1 : v1;  const int li = aw ? oi1 : i1;  // loser top1
            const float wv2 = aw ? v2 : ov2; const int wi = aw ? i2 : oi2;  // winner top2
            if (!aw) { v1 = ov1; i1 = oi1; }
            const bool sw = (wv2 < lv) || (wv2 == lv && li < wi);
            v2 = sw ? lv : wv2; i2 = sw ? li : wi;
        }

        imp_acc += p / s;
        if (lane == i1 || lane == i2) cnt_acc += 1.f;

        if (lane == 0) {
            const float e2 = expf(v2 - v1);
            const float w1 = 1.f / (1.f + e2);
            const float w2 = e2 / (1.f + e2);
            out[2 * t]     = (float)i1;
            out[2 * t + 1] = (float)i2;
            out[2 * T_TOKENS + 2 * t]     = w1;
            out[2 * T_TOKENS + 2 * t + 1] = w2;
        }
    }

    // block-level reduce: red[wave][0..63]=imp, red[wave][64..127]=cnt
    red[wv][lane]      = imp_acc;
    red[wv][64 + lane] = cnt_acc;
    __syncthreads();
    if (tid < 128) {
        float s = red[0][tid] + red[1][tid] + red[2][tid] + red[3][tid];
        bp[(size_t)blockIdx.x * 128 + tid] = s;
    }
}

// ---------------------------------------------------------------------------
// Kernel 3: reduce bp[nb][128] -> imp/cnt, then aux = E * sum(imp*cnt)/T^2
// ---------------------------------------------------------------------------
__global__ __launch_bounds__(128) void aux_kernel(
    const float* __restrict__ bp, int nb, float* __restrict__ out_aux)
{
    __shared__ float sums[128];
    const int tid = threadIdx.x;
    float s = 0.f;
    for (int b = 0; b < nb; ++b) s += bp[(size_t)b * 128 + tid];
    sums[tid] = s;
    __syncthreads();
    if (tid < 64) {
        float v = sums[tid] * sums[64 + tid];
#pragma unroll
        for (int off = 32; off; off >>= 1) v += __shfl_xor(v, off, 64);
        if (tid == 0)
            out_aux[0] = (float)E_EXP * v / ((float)T_TOKENS * (float)T_TOKENS);
    }
}

// ---------------------------------------------------------------------------
// Fallback fused kernel (no split-K workspace): 256 blocks, bp[256][128]
// ---------------------------------------------------------------------------
#define FKC   64
#define FLSTR 68
__global__ __launch_bounds__(256) void router_fused_kernel(
    const float* __restrict__ x, const float* __restrict__ gate_w,
    const float* __restrict__ ctx, float* __restrict__ out,
    float* __restrict__ bp)
{
    __shared__ float xs[TM][FLSTR];
    __shared__ float gs[E_EXP][FLSTR];
    __shared__ float ls[TM][FLSTR];
    __shared__ float red[4][128];

    const int tid = threadIdx.x;
    const int eg  = tid & 15;
    const int tg  = tid >> 4;
    const int t0  = blockIdx.x * TM;
    const int b   = t0 / N_SEQ;
    const int sr  = tid >> 4;
    const int scg = tid & 15;
    const float* ctx_row = ctx + (size_t)b * C_DIM;

    float4 acc[4][4];
#pragma unroll
    for (int i = 0; i < 4; ++i)
#pragma unroll
        for (int j = 0; j < 4; ++j) acc[i][j] = make_float4(0.f, 0.f, 0.f, 0.f);

    float4 px[4], pg[4], pc;
    auto prefetch = [&](int kc) {
        const int c0 = kc * FKC + scg * 4;
        pc = *(const float4*)(ctx_row + c0);
#pragma unroll
        for (int i = 0; i < 4; ++i) {
            px[i] = *(const float4*)(x + (size_t)(t0 + sr + 16 * i) * C_DIM + c0);
            pg[i] = *(const float4*)(gate_w + (size_t)(sr + 16 * i) * C_DIM + c0);
        }
    };

    prefetch(0);
    const int NCHUNK = C_DIM / FKC;
    for (int kc = 0; kc < NCHUNK; ++kc) {
        __syncthreads();
#pragma unroll
        for (int i = 0; i < 4; ++i) {
            float4 v = px[i];
            v.x += pc.x; v.y += pc.y; v.z += pc.z; v.w += pc.w;
            *(float4*)&xs[sr + 16 * i][scg * 4] = v;
            *(float4*)&gs[sr + 16 * i][scg * 4] = pg[i];
        }
        __syncthreads();
        if (kc + 1 < NCHUNK) prefetch(kc + 1);
#pragma unroll
        for (int cc = 0; cc < FKC; cc += 4) {
            float4 xv[4], gv[4];
#pragma unroll
            for (int i = 0; i < 4; ++i) xv[i] = *(const float4*)&xs[tg + 16 * i][cc];
#pragma unroll
            for (int j = 0; j < 4; ++j) gv[j] = *(const float4*)&gs[eg + 16 * j][cc];
#pragma unroll
            for (int i = 0; i < 4; ++i)
#pragma unroll
                for (int j = 0; j < 4; ++j) {
                    acc[i][j].x = fmaf(xv[i].x, gv[j].x, acc[i][j].x);
                    acc[i][j].y = fmaf(xv[i].y, gv[j].y, acc[i][j].y);
                    acc[i][j].z = fmaf(xv[i].z, gv[j].z, acc[i][j].z);
                    acc[i][j].w = fmaf(xv[i].w, gv[j].w, acc[i][j].w);
                }
        }
    }

    __syncthreads();
#pragma unroll
    for (int i = 0; i < 4; ++i)
#pragma unroll
        for (int j = 0; j < 4; ++j)
            ls[tg + 16 * i][eg + 16 * j] =
                (acc[i][j].x + acc[i][j].y) + (acc[i][j].z + acc[i][j].w);
    __syncthreads();

    const int wv   = tid >> 6;
    const int lane = tid & 63;
    float imp_acc = 0.f, cnt_acc = 0.f;

    for (int tt = 0; tt < 16; ++tt) {
        const int tokL = wv * 16 + tt;
        const float v = ls[tokL][lane];
        const float p = expf(v);
        float v1 = v;  int i1 = lane;
        float v2 = -INFINITY; int i2 = 0x7fffffff;
        float s = p;
#pragma unroll
        for (int off = 32; off; off >>= 1) {
            float ov1 = __shfl_xor(v1, off, 64);
            int   oi1 = __shfl_xor(i1, off, 64);
            float ov2 = __shfl_xor(v2, off, 64);
            int   oi2 = __shfl_xor(i2, off, 64);
            s += __shfl_xor(s, off, 64);
            const bool aw = (ov1 < v1) || (ov1 == v1 && i1 < oi1);
            const float lv = aw ? ov1 : v1;  const int li = aw ? oi1 : i1;
            const float wv2 = aw ? v2 : ov2; const int wi = aw ? i2 : oi2;
            if (!aw) { v1 = ov1; i1 = oi1; }
            const bool sw = (wv2 < lv) || (wv2 == lv && li < wi);
            v2 = sw ? lv : wv2; i2 = sw ? li : wi;
        }
        imp_acc += p / s;
        if (lane == i1 || lane == i2) cnt_acc += 1.f;
        if (lane == 0) {
            const int t = t0 + tokL;
            const float e2 = expf(v2 - v1);
            const float w1 = 1.f / (1.f + e2);
            const float w2 = e2 / (1.f + e2);
            out[2 * t]     = (float)i1;
            out[2 * t + 1] = (float)i2;
            out[2 * T_TOKENS + 2 * t]     = w1;
            out[2 * T_TOKENS + 2 * t + 1] = w2;
        }
    }

    red[wv][lane]      = imp_acc;
    red[wv][64 + lane] = cnt_acc;
    __syncthreads();
    if (tid < 128) {
        float s = red[0][tid] + red[1][tid] + red[2][tid] + red[3][tid];
        bp[(size_t)blockIdx.x * 128 + tid] = s;
    }
}

extern "C" void kernel_launch(void* const* d_in, const int* in_sizes, int n_in,
                              void* d_out, int out_size, void* d_ws, size_t ws_size,
                              hipStream_t stream)
{
    (void)in_sizes; (void)n_in; (void)out_size;
    const float* x      = (const float*)d_in[0];
    const float* rc     = (const float*)d_in[1];
    const float* gate_w = (const float*)d_in[2];
    const float* ctx_w  = (const float*)d_in[3];
    float* out = (float*)d_out;

    float* ctx = (float*)d_ws;                         // 8192 floats
    float* P   = ctx + 8192;                           // NSLICE*T*E floats (16.8 MB)
    float* bp  = P + (size_t)NSLICE * T_TOKENS * E_EXP; // EPB*128 floats (512 KB)

    const size_t need =
        (8192 + (size_t)NSLICE * T_TOKENS * E_EXP + (size_t)EPB * 128) * sizeof(float);

    ctx_kernel<<<2048, 256, 0, stream>>>(rc, ctx_w, ctx);
    if (ws_size >= need) {
        gemm_kernel<<<256 * NSLICE, 256, 0, stream>>>(x, gate_w, ctx, P);
        epilogue_kernel<<<EPB, 256, 0, stream>>>(P, out, bp);
        aux_kernel<<<1, 128, 0, stream>>>(bp, EPB, out + 2 * 2 * T_TOKENS);
    } else {
        float* bpf = ctx + 8192;                       // fused path: bp right after ctx
        router_fused_kernel<<<256, 256, 0, stream>>>(x, gate_w, ctx, out, bpf);
        aux_kernel<<<1, 128, 0, stream>>>(bpf, 256, out + 2 * 2 * T_TOKENS);
    }
}

// Round 5
// 272.485 us; speedup vs baseline: 1.8291x; 1.8291x over previous
//
#include <hip/hip_runtime.h>
#include <math.h>

// Problem constants (from reference): B=4, N=4096, C=2048, E=64, K=2
#define T_TOKENS 16384
#define C_DIM    2048
#define N_SEQ    4096
#define E_EXP    64
#define KC       32      // K-chunk (channels per LDS stage) — 18.4 KB/block
#define TM       64      // tokens per block
#define LSTR     36      // LDS row stride: 32+4 pad; rows collide only 2-way (free)
#define NSLICE   4       // split-K slices -> 1024 gemm blocks
#define EPB      1024    // epilogue blocks (16 tokens each)

// ---------------------------------------------------------------------------
// Kernel 1: ctx[b][j] = dot(routing_context[b,:], ctx_w[j,:])   (4 x 2048 out)
// ---------------------------------------------------------------------------
__global__ __launch_bounds__(256) void ctx_kernel(
    const float* __restrict__ rc, const float* __restrict__ ctx_w,
    float* __restrict__ ctx_out)
{
    const int w    = threadIdx.x >> 6;
    const int lane = threadIdx.x & 63;
    const int o    = blockIdx.x * 4 + w;         // 0..8191
    const int b    = o >> 11;
    const int j    = o & 2047;

    const float4* wr = (const float4*)(ctx_w + (size_t)j * C_DIM);
    const float4* rr = (const float4*)(rc + (size_t)b * C_DIM);
    float s = 0.f;
#pragma unroll
    for (int it = 0; it < 8; ++it) {
        float4 a = wr[it * 64 + lane];
        float4 c = rr[it * 64 + lane];
        s += a.x * c.x + a.y * c.y + a.z * c.z + a.w * c.w;
    }
#pragma unroll
    for (int off = 32; off; off >>= 1) s += __shfl_xor(s, off, 64);
    if (lane == 0) ctx_out[b * C_DIM + j] = s;
}

// ---------------------------------------------------------------------------
// Kernel 2a (split-K GEMM): block = 64 tokens x 64 experts x 512-ch slice.
// KC=32 -> LDS 18.4 KB/block. No minwaves bound (R2: (256,4) forced 64-VGPR
// target and spilled 600 MB to scratch).
// ---------------------------------------------------------------------------
__global__ __launch_bounds__(256) void gemm_kernel(
    const float* __restrict__ x, const float* __restrict__ gate_w,
    const float* __restrict__ ctx, float* __restrict__ P)
{
    __shared__ float xs[TM][LSTR];     // token tile (x + ctx)
    __shared__ float gs[E_EXP][LSTR];  // gate tile

    const int tid   = threadIdx.x;
    const int eg    = tid & 15;        // expert group: e = eg + 16j
    const int tg    = tid >> 4;        // token group:  t = tg + 16i
    const int tile  = blockIdx.x & 255;
    const int slice = blockIdx.x >> 8;
    const int t0    = tile * TM;
    const int b     = t0 / N_SEQ;
    const int cbase = slice * (C_DIM / NSLICE);

    const int scg = tid & 7;           // staging float4 col (0..7)
    const int sr  = tid >> 3;          // staging row (0..31); also row+32

    const float* ctx_row = ctx + (size_t)b * C_DIM;

    float4 acc[4][4];
#pragma unroll
    for (int i = 0; i < 4; ++i)
#pragma unroll
        for (int j = 0; j < 4; ++j)
            acc[i][j] = make_float4(0.f, 0.f, 0.f, 0.f);

    float4 px[2], pg[2], pc;
    auto prefetch = [&](int kc) {
        const int c0 = cbase + kc * KC + scg * 4;
        pc    = *(const float4*)(ctx_row + c0);
        px[0] = *(const float4*)(x + (size_t)(t0 + sr) * C_DIM + c0);
        px[1] = *(const float4*)(x + (size_t)(t0 + sr + 32) * C_DIM + c0);
        pg[0] = *(const float4*)(gate_w + (size_t)sr * C_DIM + c0);
        pg[1] = *(const float4*)(gate_w + (size_t)(sr + 32) * C_DIM + c0);
    };

    prefetch(0);
    const int NCHUNK = (C_DIM / NSLICE) / KC;   // 16
    for (int kc = 0; kc < NCHUNK; ++kc) {
        __syncthreads();
        {
            float4 v0 = px[0], v1 = px[1];
            v0.x += pc.x; v0.y += pc.y; v0.z += pc.z; v0.w += pc.w;
            v1.x += pc.x; v1.y += pc.y; v1.z += pc.z; v1.w += pc.w;
            *(float4*)&xs[sr][scg * 4]      = v0;
            *(float4*)&xs[sr + 32][scg * 4] = v1;
            *(float4*)&gs[sr][scg * 4]      = pg[0];
            *(float4*)&gs[sr + 32][scg * 4] = pg[1];
        }
        __syncthreads();
        if (kc + 1 < NCHUNK) prefetch(kc + 1);
#pragma unroll
        for (int cc = 0; cc < KC; cc += 4) {
            float4 xv[4], gv[4];
#pragma unroll
            for (int i = 0; i < 4; ++i) xv[i] = *(const float4*)&xs[tg + 16 * i][cc];
#pragma unroll
            for (int j = 0; j < 4; ++j) gv[j] = *(const float4*)&gs[eg + 16 * j][cc];
#pragma unroll
            for (int i = 0; i < 4; ++i)
#pragma unroll
                for (int j = 0; j < 4; ++j) {
                    acc[i][j].x = fmaf(xv[i].x, gv[j].x, acc[i][j].x);
                    acc[i][j].y = fmaf(xv[i].y, gv[j].y, acc[i][j].y);
                    acc[i][j].z = fmaf(xv[i].z, gv[j].z, acc[i][j].z);
                    acc[i][j].w = fmaf(xv[i].w, gv[j].w, acc[i][j].w);
                }
        }
    }

    float* Ps = P + (size_t)slice * T_TOKENS * E_EXP;
#pragma unroll
    for (int i = 0; i < 4; ++i)
#pragma unroll
        for (int j = 0; j < 4; ++j)
            Ps[(size_t)(t0 + tg + 16 * i) * E_EXP + eg + 16 * j] =
                (acc[i][j].x + acc[i][j].y) + (acc[i][j].z + acc[i][j].w);
}

// ---------------------------------------------------------------------------
// Kernel 2b (epilogue): sum NSLICE partials in fixed order (deterministic),
// single fused 6-step butterfly carrying (v1,i1,v2,i2,sum_exp).
// No global atomics; per-block LDS reduce -> bp[block][128].
// ---------------------------------------------------------------------------
__global__ __launch_bounds__(256) void epilogue_kernel(
    const float* __restrict__ P, float* __restrict__ out,
    float* __restrict__ bp)
{
    __shared__ float red[4][128];

    const int tid  = threadIdx.x;
    const int wv   = tid >> 6;
    const int lane = tid & 63;
    const int t0   = blockIdx.x * (T_TOKENS / EPB);   // 16 tokens per block

    float imp_acc = 0.f, cnt_acc = 0.f;

    for (int tt = 0; tt < 4; ++tt) {
        const int t = t0 + wv * 4 + tt;
        float v = 0.f;
#pragma unroll
        for (int s = 0; s < NSLICE; ++s)
            v += P[((size_t)s * T_TOKENS + t) * E_EXP + lane];

        // fused top-2 + sum(exp) butterfly (tie -> lower index, matches lax.top_k)
        const float p = expf(v);       // |v| ~< 12 -> no overflow
        float v1 = v;  int i1 = lane;
        float v2 = -INFINITY; int i2 = 0x7fffffff;
        float s = p;
#pragma unroll
        for (int off = 32; off; off >>= 1) {
            float ov1 = __shfl_xor(v1, off, 64);
            int   oi1 = __shfl_xor(i1, off, 64);
            float ov2 = __shfl_xor(v2, off, 64);
            int   oi2 = __shfl_xor(i2, off, 64);
            s += __shfl_xor(s, off, 64);
            const bool aw = (ov1 < v1) || (ov1 == v1 && i1 < oi1);
            const float lv = aw ? ov1 : v1;  const int li = aw ? oi1 : i1;  // loser top1
            const float wv2 = aw ? v2 : ov2; const int wi = aw ? i2 : oi2;  // winner top2
            if (!aw) { v1 = ov1; i1 = oi1; }
            const bool sw = (wv2 < lv) || (wv2 == lv && li < wi);
            v2 = sw ? lv : wv2; i2 = sw ? li : wi;
        }

        imp_acc += p / s;
        if (lane == i1 || lane == i2) cnt_acc += 1.f;

        if (lane == 0) {
            const float e2 = expf(v2 - v1);
            const float w1 = 1.f / (1.f + e2);
            const float w2 = e2 / (1.f + e2);
            out[2 * t]     = (float)i1;
            out[2 * t + 1] = (float)i2;
            out[2 * T_TOKENS + 2 * t]     = w1;
            out[2 * T_TOKENS + 2 * t + 1] = w2;
        }
    }

    red[wv][lane]      = imp_acc;
    red[wv][64 + lane] = cnt_acc;
    __syncthreads();
    if (tid < 128) {
        float s = red[0][tid] + red[1][tid] + red[2][tid] + red[3][tid];
        bp[(size_t)blockIdx.x * 128 + tid] = s;
    }
}

// ---------------------------------------------------------------------------
// Kernel 3: reduce bp[nb][128] -> imp/cnt sums -> aux = E*sum(imp*cnt)/T^2.
// R4 version: 128 threads x nb serial loads on ONE CU = 240 us (VALUBusy
// 0.003%). Now: 1024 threads (16 waves), float4 columns, rows strided by 32
// -> nb/32 independent loads per lane, L2-resident, latency-hidden.
// ---------------------------------------------------------------------------
__global__ __launch_bounds__(1024) void aux_kernel(
    const float* __restrict__ bp, int nb, float* __restrict__ out_aux)
{
    __shared__ float4 red[32][32];      // [row-group][float4-column]
    const int tid = threadIdx.x;
    const int c4  = tid & 31;           // float4 column 0..31 (cols 4*c4..4*c4+3)
    const int grp = tid >> 5;           // row group 0..31

    const float4* bp4 = (const float4*)bp;   // nb rows x 32 float4
    float4 s = make_float4(0.f, 0.f, 0.f, 0.f);
    for (int r = grp; r < nb; r += 32) {
        float4 v = bp4[(size_t)r * 32 + c4];
        s.x += v.x; s.y += v.y; s.z += v.z; s.w += v.w;
    }
    red[grp][c4] = s;
    __syncthreads();

    if (tid < 32) {
        float4 t = make_float4(0.f, 0.f, 0.f, 0.f);
#pragma unroll
        for (int g = 0; g < 32; ++g) {
            float4 v = red[g][tid];
            t.x += v.x; t.y += v.y; t.z += v.z; t.w += v.w;
        }
        red[0][tid] = t;                // column sums: tid<16 imp, tid>=16 cnt
    }
    __syncthreads();

    if (tid < 16) {
        float4 a = red[0][tid];         // imp[4tid..4tid+3]
        float4 b = red[0][tid + 16];    // cnt[4tid..4tid+3]
        float v = a.x * b.x + a.y * b.y + a.z * b.z + a.w * b.w;
#pragma unroll
        for (int off = 8; off; off >>= 1) v += __shfl_xor(v, off, 64);
        if (tid == 0)
            out_aux[0] = (float)E_EXP * v / ((float)T_TOKENS * (float)T_TOKENS);
    }
}

// ---------------------------------------------------------------------------
// Fallback fused kernel (no split-K workspace): 256 blocks, bp[256][128]
// ---------------------------------------------------------------------------
#define FKC   64
#define FLSTR 68
__global__ __launch_bounds__(256) void router_fused_kernel(
    const float* __restrict__ x, const float* __restrict__ gate_w,
    const float* __restrict__ ctx, float* __restrict__ out,
    float* __restrict__ bp)
{
    __shared__ float xs[TM][FLSTR];
    __shared__ float gs[E_EXP][FLSTR];
    __shared__ float ls[TM][FLSTR];
    __shared__ float red[4][128];

    const int tid = threadIdx.x;
    const int eg  = tid & 15;
    const int tg  = tid >> 4;
    const int t0  = blockIdx.x * TM;
    const int b   = t0 / N_SEQ;
    const int sr  = tid >> 4;
    const int scg = tid & 15;
    const float* ctx_row = ctx + (size_t)b * C_DIM;

    float4 acc[4][4];
#pragma unroll
    for (int i = 0; i < 4; ++i)
#pragma unroll
        for (int j = 0; j < 4; ++j) acc[i][j] = make_float4(0.f, 0.f, 0.f, 0.f);

    float4 px[4], pg[4], pc;
    auto prefetch = [&](int kc) {
        const int c0 = kc * FKC + scg * 4;
        pc = *(const float4*)(ctx_row + c0);
#pragma unroll
        for (int i = 0; i < 4; ++i) {
            px[i] = *(const float4*)(x + (size_t)(t0 + sr + 16 * i) * C_DIM + c0);
            pg[i] = *(const float4*)(gate_w + (size_t)(sr + 16 * i) * C_DIM + c0);
        }
    };

    prefetch(0);
    const int NCHUNK = C_DIM / FKC;
    for (int kc = 0; kc < NCHUNK; ++kc) {
        __syncthreads();
#pragma unroll
        for (int i = 0; i < 4; ++i) {
            float4 v = px[i];
            v.x += pc.x; v.y += pc.y; v.z += pc.z; v.w += pc.w;
            *(float4*)&xs[sr + 16 * i][scg * 4] = v;
            *(float4*)&gs[sr + 16 * i][scg * 4] = pg[i];
        }
        __syncthreads();
        if (kc + 1 < NCHUNK) prefetch(kc + 1);
#pragma unroll
        for (int cc = 0; cc < FKC; cc += 4) {
            float4 xv[4], gv[4];
#pragma unroll
            for (int i = 0; i < 4; ++i) xv[i] = *(const float4*)&xs[tg + 16 * i][cc];
#pragma unroll
            for (int j = 0; j < 4; ++j) gv[j] = *(const float4*)&gs[eg + 16 * j][cc];
#pragma unroll
            for (int i = 0; i < 4; ++i)
#pragma unroll
                for (int j = 0; j < 4; ++j) {
                    acc[i][j].x = fmaf(xv[i].x, gv[j].x, acc[i][j].x);
                    acc[i][j].y = fmaf(xv[i].y, gv[j].y, acc[i][j].y);
                    acc[i][j].z = fmaf(xv[i].z, gv[j].z, acc[i][j].z);
                    acc[i][j].w = fmaf(xv[i].w, gv[j].w, acc[i][j].w);
                }
        }
    }

    __syncthreads();
#pragma unroll
    for (int i = 0; i < 4; ++i)
#pragma unroll
        for (int j = 0; j < 4; ++j)
            ls[tg + 16 * i][eg + 16 * j] =
                (acc[i][j].x + acc[i][j].y) + (acc[i][j].z + acc[i][j].w);
    __syncthreads();

    const int wv   = tid >> 6;
    const int lane = tid & 63;
    float imp_acc = 0.f, cnt_acc = 0.f;

    for (int tt = 0; tt < 16; ++tt) {
        const int tokL = wv * 16 + tt;
        const float v = ls[tokL][lane];
        const float p = expf(v);
        float v1 = v;  int i1 = lane;
        float v2 = -INFINITY; int i2 = 0x7fffffff;
        float s = p;
#pragma unroll
        for (int off = 32; off; off >>= 1) {
            float ov1 = __shfl_xor(v1, off, 64);
            int   oi1 = __shfl_xor(i1, off, 64);
            float ov2 = __shfl_xor(v2, off, 64);
            int   oi2 = __shfl_xor(i2, off, 64);
            s += __shfl_xor(s, off, 64);
            const bool aw = (ov1 < v1) || (ov1 == v1 && i1 < oi1);
            const float lv = aw ? ov1 : v1;  const int li = aw ? oi1 : i1;
            const float wv2 = aw ? v2 : ov2; const int wi = aw ? i2 : oi2;
            if (!aw) { v1 = ov1; i1 = oi1; }
            const bool sw = (wv2 < lv) || (wv2 == lv && li < wi);
            v2 = sw ? lv : wv2; i2 = sw ? li : wi;
        }
        imp_acc += p / s;
        if (lane == i1 || lane == i2) cnt_acc += 1.f;
        if (lane == 0) {
            const int t = t0 + tokL;
            const float e2 = expf(v2 - v1);
            const float w1 = 1.f / (1.f + e2);
            const float w2 = e2 / (1.f + e2);
            out[2 * t]     = (float)i1;
            out[2 * t + 1] = (float)i2;
            out[2 * T_TOKENS + 2 * t]     = w1;
            out[2 * T_TOKENS + 2 * t + 1] = w2;
        }
    }

    red[wv][lane]      = imp_acc;
    red[wv][64 + lane] = cnt_acc;
    __syncthreads();
    if (tid < 128) {
        float s = red[0][tid] + red[1][tid] + red[2][tid] + red[3][tid];
        bp[(size_t)blockIdx.x * 128 + tid] = s;
    }
}

extern "C" void kernel_launch(void* const* d_in, const int* in_sizes, int n_in,
                              void* d_out, int out_size, void* d_ws, size_t ws_size,
                              hipStream_t stream)
{
    (void)in_sizes; (void)n_in; (void)out_size;
    const float* x      = (const float*)d_in[0];
    const float* rc     = (const float*)d_in[1];
    const float* gate_w = (const float*)d_in[2];
    const float* ctx_w  = (const float*)d_in[3];
    float* out = (float*)d_out;

    float* ctx = (float*)d_ws;                          // 8192 floats
    float* P   = ctx + 8192;                            // NSLICE*T*E floats (16.8 MB)
    float* bp  = P + (size_t)NSLICE * T_TOKENS * E_EXP; // EPB*128 floats (512 KB)

    const size_t need =
        (8192 + (size_t)NSLICE * T_TOKENS * E_EXP + (size_t)EPB * 128) * sizeof(float);

    ctx_kernel<<<2048, 256, 0, stream>>>(rc, ctx_w, ctx);
    if (ws_size >= need) {
        gemm_kernel<<<256 * NSLICE, 256, 0, stream>>>(x, gate_w, ctx, P);
        epilogue_kernel<<<EPB, 256, 0, stream>>>(P, out, bp);
        aux_kernel<<<1, 1024, 0, stream>>>(bp, EPB, out + 2 * 2 * T_TOKENS);
    } else {
        float* bpf = ctx + 8192;                        // fused path: bp after ctx
        router_fused_kernel<<<256, 256, 0, stream>>>(x, gate_w, ctx, out, bpf);
        aux_kernel<<<1, 1024, 0, stream>>>(bpf, 256, out + 2 * 2 * T_TOKENS);
    }
}

// Round 6
// 258.575 us; speedup vs baseline: 1.9275x; 1.0538x over previous
//
#include <hip/hip_runtime.h>
#include <math.h>

// Problem constants: B=4, N=4096, C=2048, E=64, K=2
#define T_TOKENS 16384
#define C_DIM    2048
#define N_SEQ    4096
#define E_EXP    64
#define NSLICE   4        // split-K slices -> 1024 gemm blocks
#define KSLICE   512      // C_DIM / NSLICE
#define KC       64       // channels staged per chunk (2 MFMA K-steps)
#define TM       64       // tokens per block
#define EPB      1024     // epilogue blocks
#define XSTR     72       // ushort stride per LDS row (64 + 8 pad, keeps 16B align)
#define GN       131072   // gate elements per split part (64*2048)

typedef __attribute__((ext_vector_type(8))) short  short8;   // 8 bf16 = 4 VGPR
typedef __attribute__((ext_vector_type(4))) float  floatx4;

// RNE fp32 -> bf16, returning bits; residual computed exactly by caller
__device__ __forceinline__ void split3(float v, ushort& h, ushort& m, ushort& l) {
    unsigned u = __float_as_uint(v);
    unsigned r = (u + 0x7fffu + ((u >> 16) & 1u)) >> 16;
    h = (ushort)r;
    float e1 = v - __uint_as_float(r << 16);          // exact
    u = __float_as_uint(e1);
    r = (u + 0x7fffu + ((u >> 16) & 1u)) >> 16;
    m = (ushort)r;
    float e2 = e1 - __uint_as_float(r << 16);         // exact
    u = __float_as_uint(e2);
    r = (u + 0x7fffu + ((u >> 16) & 1u)) >> 16;
    l = (ushort)r;
}

// ---------------------------------------------------------------------------
// Kernel 0: split gate_w (64x2048 fp32) into 3 bf16 parts, frag-ordered:
// part p, element (e,c) -> gsp[p*GN + ((c>>3)*64 + e)*8 + (c&7)]
// so a wave's B-fragment load is a coalesced dwordx4 run.
// ---------------------------------------------------------------------------
__global__ __launch_bounds__(256) void gsplit_kernel(
    const float* __restrict__ gw, ushort* __restrict__ gsp)
{
    const int idx  = blockIdx.x * 256 + threadIdx.x;   // 0..131071
    const int j    = idx & 7;
    const int e    = (idx >> 3) & 63;
    const int koct = idx >> 9;
    float g = gw[(size_t)e * C_DIM + koct * 8 + j];
    ushort h, m, l;
    split3(g, h, m, l);
    gsp[idx]          = h;
    gsp[GN + idx]     = m;
    gsp[2 * GN + idx] = l;
}

// ---------------------------------------------------------------------------
// Kernel 1: ctx[b][j] = dot(routing_context[b,:], ctx_w[j,:])
// ---------------------------------------------------------------------------
__global__ __launch_bounds__(256) void ctx_kernel(
    const float* __restrict__ rc, const float* __restrict__ ctx_w,
    float* __restrict__ ctx_out)
{
    const int w    = threadIdx.x >> 6;
    const int lane = threadIdx.x & 63;
    const int o    = blockIdx.x * 4 + w;
    const int b    = o >> 11;
    const int j    = o & 2047;

    const float4* wr = (const float4*)(ctx_w + (size_t)j * C_DIM);
    const float4* rr = (const float4*)(rc + (size_t)b * C_DIM);
    float s = 0.f;
#pragma unroll
    for (int it = 0; it < 8; ++it) {
        float4 a = wr[it * 64 + lane];
        float4 c = rr[it * 64 + lane];
        s += a.x * c.x + a.y * c.y + a.z * c.z + a.w * c.w;
    }
#pragma unroll
    for (int off = 32; off; off >>= 1) s += __shfl_xor(s, off, 64);
    if (lane == 0) ctx_out[b * C_DIM + j] = s;
}

// ---------------------------------------------------------------------------
// Kernel 2a: bf16x6 MFMA split-K GEMM. Block = 64 tok x 64 exp x 512-ch slice.
// x staged+split to LDS (3 bf16 tiles); B frags stream from pre-split gsp.
// Terms: hh, hm, mh, hl, lh, mm -> ~2^-24 relative error (fp32-class).
// R5: fp32 VALU floor = 27us issue alone; MFMA path ~3us of matrix-pipe work.
// ---------------------------------------------------------------------------
__global__ __launch_bounds__(256) void gemm_mfma_kernel(
    const float* __restrict__ x, const ushort* __restrict__ gsp,
    const float* __restrict__ ctx, float* __restrict__ P)
{
    __shared__ ushort xs[3][TM][XSTR];     // 27648 B

    const int tid   = threadIdx.x;
    const int tile  = blockIdx.x & 255;
    const int slice = blockIdx.x >> 8;
    const int t0    = tile * TM;
    const int b     = t0 / N_SEQ;
    const int cbase = slice * KSLICE;

    const int w    = tid >> 6;             // wave: token rows [16w,16w+16)
    const int lane = tid & 63;
    const int l15  = lane & 15;
    const int quad = lane >> 4;

    const int sr = tid >> 2;               // staging row 0..63
    const int sq = tid & 3;                // staging float4 phase

    const float* ctx_row = ctx + (size_t)b * C_DIM;

    floatx4 acc[4];
#pragma unroll
    for (int nt = 0; nt < 4; ++nt) acc[nt] = (floatx4){0.f, 0.f, 0.f, 0.f};

    float4 px[4];
    auto prefetch = [&](int kc) {
        const float4* xr =
            (const float4*)(x + (size_t)(t0 + sr) * C_DIM + cbase + kc * KC);
#pragma unroll
        for (int i = 0; i < 4; ++i) px[i] = xr[sq + 4 * i];
    };

    prefetch(0);
    const int NCHUNK = KSLICE / KC;        // 8
    for (int kc = 0; kc < NCHUNK; ++kc) {
        __syncthreads();                   // LDS free
        {
            const float4* cr =
                (const float4*)(ctx_row + cbase + kc * KC);
#pragma unroll
            for (int i = 0; i < 4; ++i) {
                float4 c = cr[sq + 4 * i];
                float4 v = px[i];
                v.x += c.x; v.y += c.y; v.z += c.z; v.w += c.w;
                ushort4 h, m, l;
                split3(v.x, h.x, m.x, l.x);
                split3(v.y, h.y, m.y, l.y);
                split3(v.z, h.z, m.z, l.z);
                split3(v.w, h.w, m.w, l.w);
                const int col = (sq + 4 * i) * 4;
                *(ushort4*)&xs[0][sr][col] = h;
                *(ushort4*)&xs[1][sr][col] = m;
                *(ushort4*)&xs[2][sr][col] = l;
            }
        }
        __syncthreads();                   // tiles ready
        if (kc + 1 < NCHUNK) prefetch(kc + 1);

#pragma unroll
        for (int s = 0; s < 2; ++s) {      // two K=32 steps per chunk
            const int colk = s * 32 + quad * 8;
            short8 ah = *(const short8*)&xs[0][16 * w + l15][colk];
            short8 am = *(const short8*)&xs[1][16 * w + l15][colk];
            short8 al = *(const short8*)&xs[2][16 * w + l15][colk];

            const int koct0 = (cbase + kc * KC + s * 32) >> 3;
            const int fib   = (koct0 + quad) * 64 + l15;
#pragma unroll
            for (int nt = 0; nt < 4; ++nt) {
                const size_t fo = (size_t)(fib + 16 * nt) * 8;
                short8 bh = *(const short8*)(gsp + fo);
                short8 bm = *(const short8*)(gsp + GN + fo);
                short8 bl = *(const short8*)(gsp + 2 * (size_t)GN + fo);
                acc[nt] = __builtin_amdgcn_mfma_f32_16x16x32_bf16(ah, bh, acc[nt], 0, 0, 0);
                acc[nt] = __builtin_amdgcn_mfma_f32_16x16x32_bf16(ah, bm, acc[nt], 0, 0, 0);
                acc[nt] = __builtin_amdgcn_mfma_f32_16x16x32_bf16(am, bh, acc[nt], 0, 0, 0);
                acc[nt] = __builtin_amdgcn_mfma_f32_16x16x32_bf16(ah, bl, acc[nt], 0, 0, 0);
                acc[nt] = __builtin_amdgcn_mfma_f32_16x16x32_bf16(al, bh, acc[nt], 0, 0, 0);
                acc[nt] = __builtin_amdgcn_mfma_f32_16x16x32_bf16(am, bm, acc[nt], 0, 0, 0);
            }
        }
    }

    // C/D layout: col(expert within tile)=lane&15, row(token)=quad*4+reg
    float* Ps = P + ((size_t)slice * T_TOKENS + t0 + 16 * w) * E_EXP;
#pragma unroll
    for (int nt = 0; nt < 4; ++nt)
#pragma unroll
        for (int r = 0; r < 4; ++r)
            Ps[(size_t)(quad * 4 + r) * E_EXP + 16 * nt + l15] = acc[nt][r];
}

// ---------------------------------------------------------------------------
// Kernel 2b (epilogue): deterministic slice sum, fused top-2+sumexp butterfly,
// per-block LDS reduce -> bp[block][128]. (proven R5)
// ---------------------------------------------------------------------------
__global__ __launch_bounds__(256) void epilogue_kernel(
    const float* __restrict__ P, float* __restrict__ out,
    float* __restrict__ bp)
{
    __shared__ float red[4][128];

    const int tid  = threadIdx.x;
    const int wv   = tid >> 6;
    const int lane = tid & 63;
    const int t0   = blockIdx.x * (T_TOKENS / EPB);

    float imp_acc = 0.f, cnt_acc = 0.f;

    for (int tt = 0; tt < 4; ++tt) {
        const int t = t0 + wv * 4 + tt;
        float v = 0.f;
#pragma unroll
        for (int s = 0; s < NSLICE; ++s)
            v += P[((size_t)s * T_TOKENS + t) * E_EXP + lane];

        const float p = expf(v);
        float v1 = v;  int i1 = lane;
        float v2 = -INFINITY; int i2 = 0x7fffffff;
        float s = p;
#pragma unroll
        for (int off = 32; off; off >>= 1) {
            float ov1 = __shfl_xor(v1, off, 64);
            int   oi1 = __shfl_xor(i1, off, 64);
            float ov2 = __shfl_xor(v2, off, 64);
            int   oi2 = __shfl_xor(i2, off, 64);
            s += __shfl_xor(s, off, 64);
            const bool aw = (ov1 < v1) || (ov1 == v1 && i1 < oi1);
            const float lv = aw ? ov1 : v1;  const int li = aw ? oi1 : i1;
            const float wv2 = aw ? v2 : ov2; const int wi = aw ? i2 : oi2;
            if (!aw) { v1 = ov1; i1 = oi1; }
            const bool sw = (wv2 < lv) || (wv2 == lv && li < wi);
            v2 = sw ? lv : wv2; i2 = sw ? li : wi;
        }

        imp_acc += p / s;
        if (lane == i1 || lane == i2) cnt_acc += 1.f;

        if (lane == 0) {
            const float e2 = expf(v2 - v1);
            out[2 * t]     = (float)i1;
            out[2 * t + 1] = (float)i2;
            out[2 * T_TOKENS + 2 * t]     = 1.f / (1.f + e2);
            out[2 * T_TOKENS + 2 * t + 1] = e2 / (1.f + e2);
        }
    }

    red[wv][lane]      = imp_acc;
    red[wv][64 + lane] = cnt_acc;
    __syncthreads();
    if (tid < 128) {
        float s = red[0][tid] + red[1][tid] + red[2][tid] + red[3][tid];
        bp[(size_t)blockIdx.x * 128 + tid] = s;
    }
}

// ---------------------------------------------------------------------------
// Kernel 3: parallel bp reduce -> aux loss (proven R5: 16 waves, float4 cols)
// ---------------------------------------------------------------------------
__global__ __launch_bounds__(1024) void aux_kernel(
    const float* __restrict__ bp, int nb, float* __restrict__ out_aux)
{
    __shared__ float4 red[32][32];
    const int tid = threadIdx.x;
    const int c4  = tid & 31;
    const int grp = tid >> 5;

    const float4* bp4 = (const float4*)bp;
    float4 s = make_float4(0.f, 0.f, 0.f, 0.f);
    for (int r = grp; r < nb; r += 32) {
        float4 v = bp4[(size_t)r * 32 + c4];
        s.x += v.x; s.y += v.y; s.z += v.z; s.w += v.w;
    }
    red[grp][c4] = s;
    __syncthreads();

    if (tid < 32) {
        float4 t = make_float4(0.f, 0.f, 0.f, 0.f);
#pragma unroll
        for (int g = 0; g < 32; ++g) {
            float4 v = red[g][tid];
            t.x += v.x; t.y += v.y; t.z += v.z; t.w += v.w;
        }
        red[0][tid] = t;
    }
    __syncthreads();

    if (tid < 16) {
        float4 a = red[0][tid];
        float4 b = red[0][tid + 16];
        float v = a.x * b.x + a.y * b.y + a.z * b.z + a.w * b.w;
#pragma unroll
        for (int off = 8; off; off >>= 1) v += __shfl_xor(v, off, 64);
        if (tid == 0)
            out_aux[0] = (float)E_EXP * v / ((float)T_TOKENS * (float)T_TOKENS);
    }
}

// ---------------------------------------------------------------------------
// Fallback fused fp32 kernel (proven R5) — used only if ws too small
// ---------------------------------------------------------------------------
#define FKC   64
#define FLSTR 68
__global__ __launch_bounds__(256) void router_fused_kernel(
    const float* __restrict__ x, const float* __restrict__ gate_w,
    const float* __restrict__ ctx, float* __restrict__ out,
    float* __restrict__ bp)
{
    __shared__ float xs[TM][FLSTR];
    __shared__ float gs[E_EXP][FLSTR];
    __shared__ float ls[TM][FLSTR];
    __shared__ float red[4][128];

    const int tid = threadIdx.x;
    const int eg  = tid & 15;
    const int tg  = tid >> 4;
    const int t0  = blockIdx.x * TM;
    const int b   = t0 / N_SEQ;
    const int sr  = tid >> 4;
    const int scg = tid & 15;
    const float* ctx_row = ctx + (size_t)b * C_DIM;

    float4 acc[4][4];
#pragma unroll
    for (int i = 0; i < 4; ++i)
#pragma unroll
        for (int j = 0; j < 4; ++j) acc[i][j] = make_float4(0.f, 0.f, 0.f, 0.f);

    float4 px[4], pg[4], pc;
    auto prefetch = [&](int kc) {
        const int c0 = kc * FKC + scg * 4;
        pc = *(const float4*)(ctx_row + c0);
#pragma unroll
        for (int i = 0; i < 4; ++i) {
            px[i] = *(const float4*)(x + (size_t)(t0 + sr + 16 * i) * C_DIM + c0);
            pg[i] = *(const float4*)(gate_w + (size_t)(sr + 16 * i) * C_DIM + c0);
        }
    };

    prefetch(0);
    const int NCHUNK = C_DIM / FKC;
    for (int kc = 0; kc < NCHUNK; ++kc) {
        __syncthreads();
#pragma unroll
        for (int i = 0; i < 4; ++i) {
            float4 v = px[i];
            v.x += pc.x; v.y += pc.y; v.z += pc.z; v.w += pc.w;
            *(float4*)&xs[sr + 16 * i][scg * 4] = v;
            *(float4*)&gs[sr + 16 * i][scg * 4] = pg[i];
        }
        __syncthreads();
        if (kc + 1 < NCHUNK) prefetch(kc + 1);
#pragma unroll
        for (int cc = 0; cc < FKC; cc += 4) {
            float4 xv[4], gv[4];
#pragma unroll
            for (int i = 0; i < 4; ++i) xv[i] = *(const float4*)&xs[tg + 16 * i][cc];
#pragma unroll
            for (int j = 0; j < 4; ++j) gv[j] = *(const float4*)&gs[eg + 16 * j][cc];
#pragma unroll
            for (int i = 0; i < 4; ++i)
#pragma unroll
                for (int j = 0; j < 4; ++j) {
                    acc[i][j].x = fmaf(xv[i].x, gv[j].x, acc[i][j].x);
                    acc[i][j].y = fmaf(xv[i].y, gv[j].y, acc[i][j].y);
                    acc[i][j].z = fmaf(xv[i].z, gv[j].z, acc[i][j].z);
                    acc[i][j].w = fmaf(xv[i].w, gv[j].w, acc[i][j].w);
                }
        }
    }

    __syncthreads();
#pragma unroll
    for (int i = 0; i < 4; ++i)
#pragma unroll
        for (int j = 0; j < 4; ++j)
            ls[tg + 16 * i][eg + 16 * j] =
                (acc[i][j].x + acc[i][j].y) + (acc[i][j].z + acc[i][j].w);
    __syncthreads();

    const int wv   = tid >> 6;
    const int lane = tid & 63;
    float imp_acc = 0.f, cnt_acc = 0.f;

    for (int tt = 0; tt < 16; ++tt) {
        const int tokL = wv * 16 + tt;
        const float v = ls[tokL][lane];
        const float p = expf(v);
        float v1 = v;  int i1 = lane;
        float v2 = -INFINITY; int i2 = 0x7fffffff;
        float s = p;
#pragma unroll
        for (int off = 32; off; off >>= 1) {
            float ov1 = __shfl_xor(v1, off, 64);
            int   oi1 = __shfl_xor(i1, off, 64);
            float ov2 = __shfl_xor(v2, off, 64);
            int   oi2 = __shfl_xor(i2, off, 64);
            s += __shfl_xor(s, off, 64);
            const bool aw = (ov1 < v1) || (ov1 == v1 && i1 < oi1);
            const float lv = aw ? ov1 : v1;  const int li = aw ? oi1 : i1;
            const float wv2 = aw ? v2 : ov2; const int wi = aw ? i2 : oi2;
            if (!aw) { v1 = ov1; i1 = oi1; }
            const bool sw = (wv2 < lv) || (wv2 == lv && li < wi);
            v2 = sw ? lv : wv2; i2 = sw ? li : wi;
        }
        imp_acc += p / s;
        if (lane == i1 || lane == i2) cnt_acc += 1.f;
        if (lane == 0) {
            const int t = t0 + tokL;
            const float e2 = expf(v2 - v1);
            out[2 * t]     = (float)i1;
            out[2 * t + 1] = (float)i2;
            out[2 * T_TOKENS + 2 * t]     = 1.f / (1.f + e2);
            out[2 * T_TOKENS + 2 * t + 1] = e2 / (1.f + e2);
        }
    }

    red[wv][lane]      = imp_acc;
    red[wv][64 + lane] = cnt_acc;
    __syncthreads();
    if (tid < 128) {
        float s = red[0][tid] + red[1][tid] + red[2][tid] + red[3][tid];
        bp[(size_t)blockIdx.x * 128 + tid] = s;
    }
}

extern "C" void kernel_launch(void* const* d_in, const int* in_sizes, int n_in,
                              void* d_out, int out_size, void* d_ws, size_t ws_size,
                              hipStream_t stream)
{
    (void)in_sizes; (void)n_in; (void)out_size;
    const float* x      = (const float*)d_in[0];
    const float* rc     = (const float*)d_in[1];
    const float* gate_w = (const float*)d_in[2];
    const float* ctx_w  = (const float*)d_in[3];
    float* out = (float*)d_out;

    float*  ctx = (float*)d_ws;                           // 8192 floats
    float*  bp  = ctx + 8192;                             // EPB*128 floats
    float*  P   = bp + (size_t)EPB * 128;                 // NSLICE*T*E floats
    ushort* gsp = (ushort*)(P + (size_t)NSLICE * T_TOKENS * E_EXP); // 3*GN ushort

    const size_t need =
        (8192 + (size_t)EPB * 128 + (size_t)NSLICE * T_TOKENS * E_EXP) * sizeof(float)
        + (size_t)3 * GN * sizeof(ushort);

    ctx_kernel<<<2048, 256, 0, stream>>>(rc, ctx_w, ctx);
    if (ws_size >= need) {
        gsplit_kernel<<<GN / 256, 256, 0, stream>>>(gate_w, gsp);
        gemm_mfma_kernel<<<256 * NSLICE, 256, 0, stream>>>(x, gsp, ctx, P);
        epilogue_kernel<<<EPB, 256, 0, stream>>>(P, out, bp);
        aux_kernel<<<1, 1024, 0, stream>>>(bp, EPB, out + 2 * 2 * T_TOKENS);
    } else {
        router_fused_kernel<<<256, 256, 0, stream>>>(x, gate_w, ctx, out, bp);
        aux_kernel<<<1, 1024, 0, stream>>>(bp, 256, out + 2 * 2 * T_TOKENS);
    }
}

// Round 7
// 246.268 us; speedup vs baseline: 2.0238x; 1.0500x over previous
//
#include <hip/hip_runtime.h>
#include <math.h>

// Problem constants: B=4, N=4096, C=2048, E=64, K=2
#define T_TOKENS 16384
#define C_DIM    2048
#define N_SEQ    4096
#define E_EXP    64
#define NSLICE   4        // split-K slices
#define KSLICE   512      // C_DIM / NSLICE
#define EPB      1024     // epilogue blocks
#define GN       131072   // gate elements per split part (64*2048)

typedef __attribute__((ext_vector_type(8))) short  short8;   // 8 bf16 = 4 VGPR
typedef __attribute__((ext_vector_type(4))) float  floatx4;

// ---- exact 3-way bf16 decomposition (truncation; residuals exact) ----------
__device__ __forceinline__ void splitv(float v, ushort& h, ushort& m, ushort& l) {
    unsigned u = __float_as_uint(v);
    h = (ushort)(u >> 16);
    float f1 = v - __uint_as_float(u & 0xffff0000u);       // exact
    unsigned u1 = __float_as_uint(f1);
    m = (ushort)(u1 >> 16);
    float f2 = f1 - __uint_as_float(u1 & 0xffff0000u);     // exact
    l = (ushort)(__float_as_uint(f2) >> 16);
}

__device__ __forceinline__ void splitpack8(const float4& a, const float4& b,
                                           short8& h, short8& m, short8& l) {
    ushort hh, mm, ll;
    splitv(a.x, hh, mm, ll); h[0] = hh; m[0] = mm; l[0] = ll;
    splitv(a.y, hh, mm, ll); h[1] = hh; m[1] = mm; l[1] = ll;
    splitv(a.z, hh, mm, ll); h[2] = hh; m[2] = mm; l[2] = ll;
    splitv(a.w, hh, mm, ll); h[3] = hh; m[3] = mm; l[3] = ll;
    splitv(b.x, hh, mm, ll); h[4] = hh; m[4] = mm; l[4] = ll;
    splitv(b.y, hh, mm, ll); h[5] = hh; m[5] = mm; l[5] = ll;
    splitv(b.z, hh, mm, ll); h[6] = hh; m[6] = mm; l[6] = ll;
    splitv(b.w, hh, mm, ll); h[7] = hh; m[7] = mm; l[7] = ll;
}

// RNE split for the one-time gate_w preprocessing
__device__ __forceinline__ void split3rne(float v, ushort& h, ushort& m, ushort& l) {
    unsigned u = __float_as_uint(v);
    unsigned r = (u + 0x7fffu + ((u >> 16) & 1u)) >> 16;
    h = (ushort)r;
    float e1 = v - __uint_as_float(r << 16);
    u = __float_as_uint(e1);
    r = (u + 0x7fffu + ((u >> 16) & 1u)) >> 16;
    m = (ushort)r;
    float e2 = e1 - __uint_as_float(r << 16);
    l = (ushort)(__float_as_uint(e2) >> 16);
}

// ---------------------------------------------------------------------------
// Kernel 1: ctx[b][j] = dot(routing_context[b,:], ctx_w[j,:])
// ---------------------------------------------------------------------------
__global__ __launch_bounds__(256) void ctx_kernel(
    const float* __restrict__ rc, const float* __restrict__ ctx_w,
    float* __restrict__ ctx_out)
{
    const int w    = threadIdx.x >> 6;
    const int lane = threadIdx.x & 63;
    const int o    = blockIdx.x * 4 + w;
    const int b    = o >> 11;
    const int j    = o & 2047;

    const float4* wr = (const float4*)(ctx_w + (size_t)j * C_DIM);
    const float4* rr = (const float4*)(rc + (size_t)b * C_DIM);
    float s = 0.f;
#pragma unroll
    for (int it = 0; it < 8; ++it) {
        float4 a = wr[it * 64 + lane];
        float4 c = rr[it * 64 + lane];
        s += a.x * c.x + a.y * c.y + a.z * c.z + a.w * c.w;
    }
#pragma unroll
    for (int off = 32; off; off >>= 1) s += __shfl_xor(s, off, 64);
    if (lane == 0) ctx_out[b * C_DIM + j] = s;
}

// ---------------------------------------------------------------------------
// Kernel 2 (prep): blocks 0..511 split gate_w into 3 frag-ordered bf16 parts
// (part p, (e,c) -> gsp[p*GN + ((c>>3)*64+e)*8 + (c&7)]); blocks 512..575
// compute cl[b][e] = dot(ctx[b,:], gate_w[e,:]) (ctx decoupled from gemm:
// logits = x@W^T + ctx@W^T, second term is 4x64).
// ---------------------------------------------------------------------------
__global__ __launch_bounds__(256) void prep_kernel(
    const float* __restrict__ gw, const float* __restrict__ ctx,
    ushort* __restrict__ gsp, float* __restrict__ cl)
{
    if (blockIdx.x < 512) {
        const int idx  = blockIdx.x * 256 + threadIdx.x;   // 0..131071
        const int j    = idx & 7;
        const int e    = (idx >> 3) & 63;
        const int koct = idx >> 9;
        float g = gw[(size_t)e * C_DIM + koct * 8 + j];
        ushort h, m, l;
        split3rne(g, h, m, l);
        gsp[idx]          = h;
        gsp[GN + idx]     = m;
        gsp[2 * GN + idx] = l;
    } else {
        const int lane = threadIdx.x & 63;
        const int pk   = (blockIdx.x - 512) * 4 + (threadIdx.x >> 6); // 0..255
        const int b    = pk >> 6;
        const int e    = pk & 63;
        const float4* wr = (const float4*)(gw + (size_t)e * C_DIM);
        const float4* cr = (const float4*)(ctx + (size_t)b * C_DIM);
        float s = 0.f;
#pragma unroll
        for (int it = 0; it < 8; ++it) {
            float4 a = wr[it * 64 + lane];
            float4 c = cr[it * 64 + lane];
            s += a.x * c.x + a.y * c.y + a.z * c.z + a.w * c.w;
        }
#pragma unroll
        for (int off = 32; off; off >>= 1) s += __shfl_xor(s, off, 64);
        if (lane == 0) cl[pk] = s;
    }
}

// ---------------------------------------------------------------------------
// Kernel 3: barrier-free LDS-free bf16x6 MFMA split-K GEMM.
// Wave = 32 tokens (2 strips of 16) x 64 experts x 512-ch slice.
// Each A element loaded+split by exactly one thread (registers only);
// B fragments stream from pre-split gsp (L2-resident). No __syncthreads.
// R6: LDS staging cost 2.36M conflict cyc + 16 barrier drains -> removed.
// ---------------------------------------------------------------------------
__global__ __launch_bounds__(256) void gemm_mfma_kernel(
    const float* __restrict__ x, const ushort* __restrict__ gsp,
    float* __restrict__ P)
{
    const int tid   = threadIdx.x;
    const int wv    = tid >> 6;
    const int lane  = tid & 63;
    const int l15   = lane & 15;
    const int quad  = lane >> 4;
    const int tile  = blockIdx.x & 127;     // 128 tiles x 128 tokens
    const int slice = blockIdx.x >> 7;      // 0..3
    const int tw    = tile * 128 + wv * 32; // wave token base
    const int cbase = slice * KSLICE;

    floatx4 acc[2][4];
#pragma unroll
    for (int s = 0; s < 2; ++s)
#pragma unroll
        for (int nt = 0; nt < 4; ++nt) acc[s][nt] = (floatx4){0.f, 0.f, 0.f, 0.f};

    const float* xr0 = x + (size_t)(tw + l15) * C_DIM + cbase + quad * 8;
    const float* xr1 = xr0 + (size_t)16 * C_DIM;
    const ushort* bb = gsp + ((size_t)((cbase >> 3) + quad) * 64 + l15) * 8;

#pragma unroll 2
    for (int ks = 0; ks < KSLICE / 32; ++ks) {       // 16 K=32 steps
        float4 a00 = *(const float4*)(xr0 + ks * 32);
        float4 a01 = *(const float4*)(xr0 + ks * 32 + 4);
        float4 a10 = *(const float4*)(xr1 + ks * 32);
        float4 a11 = *(const float4*)(xr1 + ks * 32 + 4);
        short8 ah0, am0, al0, ah1, am1, al1;
        splitpack8(a00, a01, ah0, am0, al0);
        splitpack8(a10, a11, ah1, am1, al1);

        const ushort* bks = bb + (size_t)ks * 4 * 64 * 8;  // 4 koct per step
#pragma unroll
        for (int nt = 0; nt < 4; ++nt) {
            const ushort* bp_ = bks + (size_t)(16 * nt) * 8;
            short8 bh = *(const short8*)(bp_);
            short8 bm = *(const short8*)(bp_ + GN);
            short8 bl = *(const short8*)(bp_ + 2 * (size_t)GN);
            acc[0][nt] = __builtin_amdgcn_mfma_f32_16x16x32_bf16(ah0, bh, acc[0][nt], 0, 0, 0);
            acc[0][nt] = __builtin_amdgcn_mfma_f32_16x16x32_bf16(ah0, bm, acc[0][nt], 0, 0, 0);
            acc[0][nt] = __builtin_amdgcn_mfma_f32_16x16x32_bf16(am0, bh, acc[0][nt], 0, 0, 0);
            acc[0][nt] = __builtin_amdgcn_mfma_f32_16x16x32_bf16(ah0, bl, acc[0][nt], 0, 0, 0);
            acc[0][nt] = __builtin_amdgcn_mfma_f32_16x16x32_bf16(al0, bh, acc[0][nt], 0, 0, 0);
            acc[0][nt] = __builtin_amdgcn_mfma_f32_16x16x32_bf16(am0, bm, acc[0][nt], 0, 0, 0);
            acc[1][nt] = __builtin_amdgcn_mfma_f32_16x16x32_bf16(ah1, bh, acc[1][nt], 0, 0, 0);
            acc[1][nt] = __builtin_amdgcn_mfma_f32_16x16x32_bf16(ah1, bm, acc[1][nt], 0, 0, 0);
            acc[1][nt] = __builtin_amdgcn_mfma_f32_16x16x32_bf16(am1, bh, acc[1][nt], 0, 0, 0);
            acc[1][nt] = __builtin_amdgcn_mfma_f32_16x16x32_bf16(ah1, bl, acc[1][nt], 0, 0, 0);
            acc[1][nt] = __builtin_amdgcn_mfma_f32_16x16x32_bf16(al1, bh, acc[1][nt], 0, 0, 0);
            acc[1][nt] = __builtin_amdgcn_mfma_f32_16x16x32_bf16(am1, bm, acc[1][nt], 0, 0, 0);
        }
    }

    // C/D layout (R6-verified): col=l15 (expert 16nt+l15), row=quad*4+r
    float* Ps = P + ((size_t)slice * T_TOKENS + tw) * E_EXP;
#pragma unroll
    for (int s = 0; s < 2; ++s)
#pragma unroll
        for (int nt = 0; nt < 4; ++nt)
#pragma unroll
            for (int r = 0; r < 4; ++r)
                Ps[(size_t)(s * 16 + quad * 4 + r) * E_EXP + 16 * nt + l15] =
                    acc[s][nt][r];
}

// ---------------------------------------------------------------------------
// Kernel 4 (epilogue): deterministic slice sum + cl[b][e], fused
// top-2+sumexp butterfly, per-block LDS reduce -> bp[block][128].
// ---------------------------------------------------------------------------
__global__ __launch_bounds__(256) void epilogue_kernel(
    const float* __restrict__ P, const float* __restrict__ cl,
    float* __restrict__ out, float* __restrict__ bp)
{
    __shared__ float red[4][128];

    const int tid  = threadIdx.x;
    const int wv   = tid >> 6;
    const int lane = tid & 63;
    const int t0   = blockIdx.x * (T_TOKENS / EPB);     // 16 tokens
    const float clv = cl[(t0 >> 12) * 64 + lane];       // batch = t0/4096

    float imp_acc = 0.f, cnt_acc = 0.f;

    for (int tt = 0; tt < 4; ++tt) {
        const int t = t0 + wv * 4 + tt;
        float v = clv;
#pragma unroll
        for (int s = 0; s < NSLICE; ++s)
            v += P[((size_t)s * T_TOKENS + t) * E_EXP + lane];

        const float p = expf(v);
        float v1 = v;  int i1 = lane;
        float v2 = -INFINITY; int i2 = 0x7fffffff;
        float s = p;
#pragma unroll
        for (int off = 32; off; off >>= 1) {
            float ov1 = __shfl_xor(v1, off, 64);
            int   oi1 = __shfl_xor(i1, off, 64);
            float ov2 = __shfl_xor(v2, off, 64);
            int   oi2 = __shfl_xor(i2, off, 64);
            s += __shfl_xor(s, off, 64);
            const bool aw = (ov1 < v1) || (ov1 == v1 && i1 < oi1);
            const float lv = aw ? ov1 : v1;  const int li = aw ? oi1 : i1;
            const float wv2 = aw ? v2 : ov2; const int wi = aw ? i2 : oi2;
            if (!aw) { v1 = ov1; i1 = oi1; }
            const bool sw = (wv2 < lv) || (wv2 == lv && li < wi);
            v2 = sw ? lv : wv2; i2 = sw ? li : wi;
        }

        imp_acc += p / s;
        if (lane == i1 || lane == i2) cnt_acc += 1.f;

        if (lane == 0) {
            const float e2 = expf(v2 - v1);
            out[2 * t]     = (float)i1;
            out[2 * t + 1] = (float)i2;
            out[2 * T_TOKENS + 2 * t]     = 1.f / (1.f + e2);
            out[2 * T_TOKENS + 2 * t + 1] = e2 / (1.f + e2);
        }
    }

    red[wv][lane]      = imp_acc;
    red[wv][64 + lane] = cnt_acc;
    __syncthreads();
    if (tid < 128) {
        float s = red[0][tid] + red[1][tid] + red[2][tid] + red[3][tid];
        bp[(size_t)blockIdx.x * 128 + tid] = s;
    }
}

// ---------------------------------------------------------------------------
// Kernel 5: parallel bp reduce -> aux loss (proven R5)
// ---------------------------------------------------------------------------
__global__ __launch_bounds__(1024) void aux_kernel(
    const float* __restrict__ bp, int nb, float* __restrict__ out_aux)
{
    __shared__ float4 red[32][32];
    const int tid = threadIdx.x;
    const int c4  = tid & 31;
    const int grp = tid >> 5;

    const float4* bp4 = (const float4*)bp;
    float4 s = make_float4(0.f, 0.f, 0.f, 0.f);
    for (int r = grp; r < nb; r += 32) {
        float4 v = bp4[(size_t)r * 32 + c4];
        s.x += v.x; s.y += v.y; s.z += v.z; s.w += v.w;
    }
    red[grp][c4] = s;
    __syncthreads();

    if (tid < 32) {
        float4 t = make_float4(0.f, 0.f, 0.f, 0.f);
#pragma unroll
        for (int g = 0; g < 32; ++g) {
            float4 v = red[g][tid];
            t.x += v.x; t.y += v.y; t.z += v.z; t.w += v.w;
        }
        red[0][tid] = t;
    }
    __syncthreads();

    if (tid < 16) {
        float4 a = red[0][tid];
        float4 b = red[0][tid + 16];
        float v = a.x * b.x + a.y * b.y + a.z * b.z + a.w * b.w;
#pragma unroll
        for (int off = 8; off; off >>= 1) v += __shfl_xor(v, off, 64);
        if (tid == 0)
            out_aux[0] = (float)E_EXP * v / ((float)T_TOKENS * (float)T_TOKENS);
    }
}

// ---------------------------------------------------------------------------
// Fallback fused fp32 kernel (proven R5) — used only if ws too small
// ---------------------------------------------------------------------------
#define TM    64
#define FKC   64
#define FLSTR 68
__global__ __launch_bounds__(256) void router_fused_kernel(
    const float* __restrict__ x, const float* __restrict__ gate_w,
    const float* __restrict__ ctx, float* __restrict__ out,
    float* __restrict__ bp)
{
    __shared__ float xs[TM][FLSTR];
    __shared__ float gs[E_EXP][FLSTR];
    __shared__ float ls[TM][FLSTR];
    __shared__ float red[4][128];

    const int tid = threadIdx.x;
    const int eg  = tid & 15;
    const int tg  = tid >> 4;
    const int t0  = blockIdx.x * TM;
    const int b   = t0 / N_SEQ;
    const int sr  = tid >> 4;
    const int scg = tid & 15;
    const float* ctx_row = ctx + (size_t)b * C_DIM;

    float4 acc[4][4];
#pragma unroll
    for (int i = 0; i < 4; ++i)
#pragma unroll
        for (int j = 0; j < 4; ++j) acc[i][j] = make_float4(0.f, 0.f, 0.f, 0.f);

    float4 px[4], pg[4], pc;
    auto prefetch = [&](int kc) {
        const int c0 = kc * FKC + scg * 4;
        pc = *(const float4*)(ctx_row + c0);
#pragma unroll
        for (int i = 0; i < 4; ++i) {
            px[i] = *(const float4*)(x + (size_t)(t0 + sr + 16 * i) * C_DIM + c0);
            pg[i] = *(const float4*)(gate_w + (size_t)(sr + 16 * i) * C_DIM + c0);
        }
    };

    prefetch(0);
    const int NCHUNK = C_DIM / FKC;
    for (int kc = 0; kc < NCHUNK; ++kc) {
        __syncthreads();
#pragma unroll
        for (int i = 0; i < 4; ++i) {
            float4 v = px[i];
            v.x += pc.x; v.y += pc.y; v.z += pc.z; v.w += pc.w;
            *(float4*)&xs[sr + 16 * i][scg * 4] = v;
            *(float4*)&gs[sr + 16 * i][scg * 4] = pg[i];
        }
        __syncthreads();
        if (kc + 1 < NCHUNK) prefetch(kc + 1);
#pragma unroll
        for (int cc = 0; cc < FKC; cc += 4) {
            float4 xv[4], gv[4];
#pragma unroll
            for (int i = 0; i < 4; ++i) xv[i] = *(const float4*)&xs[tg + 16 * i][cc];
#pragma unroll
            for (int j = 0; j < 4; ++j) gv[j] = *(const float4*)&gs[eg + 16 * j][cc];
#pragma unroll
            for (int i = 0; i < 4; ++i)
#pragma unroll
                for (int j = 0; j < 4; ++j) {
                    acc[i][j].x = fmaf(xv[i].x, gv[j].x, acc[i][j].x);
                    acc[i][j].y = fmaf(xv[i].y, gv[j].y, acc[i][j].y);
                    acc[i][j].z = fmaf(xv[i].z, gv[j].z, acc[i][j].z);
                    acc[i][j].w = fmaf(xv[i].w, gv[j].w, acc[i][j].w);
                }
        }
    }

    __syncthreads();
#pragma unroll
    for (int i = 0; i < 4; ++i)
#pragma unroll
        for (int j = 0; j < 4; ++j)
            ls[tg + 16 * i][eg + 16 * j] =
                (acc[i][j].x + acc[i][j].y) + (acc[i][j].z + acc[i][j].w);
    __syncthreads();

    const int wv   = tid >> 6;
    const int lane = tid & 63;
    float imp_acc = 0.f, cnt_acc = 0.f;

    for (int tt = 0; tt < 16; ++tt) {
        const int tokL = wv * 16 + tt;
        const float v = ls[tokL][lane];
        const float p = expf(v);
        float v1 = v;  int i1 = lane;
        float v2 = -INFINITY; int i2 = 0x7fffffff;
        float s = p;
#pragma unroll
        for (int off = 32; off; off >>= 1) {
            float ov1 = __shfl_xor(v1, off, 64);
            int   oi1 = __shfl_xor(i1, off, 64);
            float ov2 = __shfl_xor(v2, off, 64);
            int   oi2 = __shfl_xor(i2, off, 64);
            s += __shfl_xor(s, off, 64);
            const bool aw = (ov1 < v1) || (ov1 == v1 && i1 < oi1);
            const float lv = aw ? ov1 : v1;  const int li = aw ? oi1 : i1;
            const float wv2 = aw ? v2 : ov2; const int wi = aw ? i2 : oi2;
            if (!aw) { v1 = ov1; i1 = oi1; }
            const bool sw = (wv2 < lv) || (wv2 == lv && li < wi);
            v2 = sw ? lv : wv2; i2 = sw ? li : wi;
        }
        imp_acc += p / s;
        if (lane == i1 || lane == i2) cnt_acc += 1.f;
        if (lane == 0) {
            const int t = t0 + tokL;
            const float e2 = expf(v2 - v1);
            out[2 * t]     = (float)i1;
            out[2 * t + 1] = (float)i2;
            out[2 * T_TOKENS + 2 * t]     = 1.f / (1.f + e2);
            out[2 * T_TOKENS + 2 * t + 1] = e2 / (1.f + e2);
        }
    }

    red[wv][lane]      = imp_acc;
    red[wv][64 + lane] = cnt_acc;
    __syncthreads();
    if (tid < 128) {
        float s = red[0][tid] + red[1][tid] + red[2][tid] + red[3][tid];
        bp[(size_t)blockIdx.x * 128 + tid] = s;
    }
}

extern "C" void kernel_launch(void* const* d_in, const int* in_sizes, int n_in,
                              void* d_out, int out_size, void* d_ws, size_t ws_size,
                              hipStream_t stream)
{
    (void)in_sizes; (void)n_in; (void)out_size;
    const float* x      = (const float*)d_in[0];
    const float* rc     = (const float*)d_in[1];
    const float* gate_w = (const float*)d_in[2];
    const float* ctx_w  = (const float*)d_in[3];
    float* out = (float*)d_out;

    float*  ctx = (float*)d_ws;                            // 8192 f
    float*  cl  = ctx + 8192;                              // 256 f
    float*  bp  = cl + 256;                                // EPB*128 f
    float*  P   = bp + (size_t)EPB * 128;                  // NSLICE*T*E f
    ushort* gsp = (ushort*)(P + (size_t)NSLICE * T_TOKENS * E_EXP); // 3*GN us

    const size_t need =
        (8192 + 256 + (size_t)EPB * 128 + (size_t)NSLICE * T_TOKENS * E_EXP)
            * sizeof(float)
        + (size_t)3 * GN * sizeof(ushort);

    ctx_kernel<<<2048, 256, 0, stream>>>(rc, ctx_w, ctx);
    if (ws_size >= need) {
        prep_kernel<<<576, 256, 0, stream>>>(gate_w, ctx, gsp, cl);
        gemm_mfma_kernel<<<128 * NSLICE, 256, 0, stream>>>(x, gsp, P);
        epilogue_kernel<<<EPB, 256, 0, stream>>>(P, cl, out, bp);
        aux_kernel<<<1, 1024, 0, stream>>>(bp, EPB, out + 2 * 2 * T_TOKENS);
    } else {
        router_fused_kernel<<<256, 256, 0, stream>>>(x, gate_w, ctx, out, bp);
        aux_kernel<<<1, 1024, 0, stream>>>(bp, 256, out + 2 * 2 * T_TOKENS);
    }
}